// Round 9
// baseline (365.279 us; speedup 1.0000x reference)
//
#include <hip/hip_runtime.h>
#include <math.h>

// LatentCompressedAttention on MI355X (gfx950), bf16-MFMA pipeline.
// B=2, S=2048, D=2048, H=16, Dh=128, LATENT=512, ROPE=64.

typedef __attribute__((ext_vector_type(8))) short bf16x8;    // 8 bf16 in 4 VGPRs
typedef __attribute__((ext_vector_type(4))) float f32x4;
typedef __attribute__((ext_vector_type(16))) float f32x16;

#define GLDS(gp, lp)                                                         \
  __builtin_amdgcn_global_load_lds(                                          \
      (const __attribute__((address_space(1))) void*)(gp),                   \
      (__attribute__((address_space(3))) void*)(lp), 16, 0, 0)

__device__ __forceinline__ short f2bf(float f) {
  unsigned u = __builtin_bit_cast(unsigned, f);
  u += 0x7fffu + ((u >> 16) & 1u);          // RNE
  return (short)(u >> 16);
}
__device__ __forceinline__ float b2f(short x) {
  unsigned u = ((unsigned)(unsigned short)x) << 16;
  return __builtin_bit_cast(float, u);
}
// HW packed f32->bf16 (v_cvt_pk_bf16_f32; lo in low short)
__device__ __forceinline__ unsigned cvtpk(float lo, float hi) {
  unsigned r;
  asm("v_cvt_pk_bf16_f32 %0, %1, %2" : "=v"(r) : "v"(lo), "v"(hi));
  return r;
}

// ---------------------------------------------------------------- casts ----
__global__ void cast4_kernel(const float* __restrict__ x, short* __restrict__ xb, int n4) {
  int i = blockIdx.x * blockDim.x + threadIdx.x;
  if (i < n4) {
    float4 v = ((const float4*)x)[i];
    ushort4 o;
    o.x = (unsigned short)f2bf(v.x);
    o.y = (unsigned short)f2bf(v.y);
    o.z = (unsigned short)f2bf(v.z);
    o.w = (unsigned short)f2bf(v.w);
    ((ushort4*)xb)[i] = o;
  }
}

// W[K][N] fp32 -> Wt[N][K] bf16; gridDim.z selects one of two weight pairs.
__global__ void transpose_cast2_kernel(const float* __restrict__ W0, short* __restrict__ T0,
                                       const float* __restrict__ W1, short* __restrict__ T1,
                                       int K, int N) {
  const float* W = blockIdx.z ? W1 : W0;
  short* Wt = blockIdx.z ? T1 : T0;
  __shared__ float tile[32][33];
  int n0 = blockIdx.x * 32, k0 = blockIdx.y * 32;
  int tx = threadIdx.x & 31, ty = threadIdx.x >> 5;   // ty in 0..7
#pragma unroll
  for (int i = 0; i < 4; ++i)
    tile[ty + i * 8][tx] = W[(size_t)(k0 + ty + i * 8) * N + n0 + tx];
  __syncthreads();
#pragma unroll
  for (int i = 0; i < 4; ++i)
    Wt[(size_t)(n0 + ty + i * 8) * K + k0 + tx] = f2bf(tile[tx][ty + i * 8]);
}

// cos/sin table: [S=2048][32]
__global__ void rope_tab_kernel(const int* __restrict__ pos, float* __restrict__ cosT,
                                float* __restrict__ sinT) {
  int idx = blockIdx.x * 256 + threadIdx.x;
  if (idx < 2048 * 32) {
    int s = idx >> 5, i = idx & 31;
    float p = (float)pos[s];
    float freq = p * powf(10000.0f, -(float)(2 * i) / 64.0f);
    float sv, cv;
    sincosf(freq, &sv, &cv);
    cosT[idx] = cv;
    sinT[idx] = sv;
  }
}

// ----------------------------------------------------------------- GEMM ----
// R7-verified. C = A[M,K] @ Bt[N,K]^T, bf16, 128x128 tile, BK=64, 4 waves,
// T2 XOR-swizzle (rule 21: linear dest + inv-swz source + swz read).
template <int MODE>
__device__ __forceinline__ void gemm_core(const short* __restrict__ A,
                                          const short* __restrict__ Bt,
                                          void* __restrict__ Cv,
                                          int N, int K, int bm, int bn,
                                          short* sm) {
  const int tid  = threadIdx.x;
  const int lane = tid & 63;
  const int w    = tid >> 6;
  const int col  = lane & 15, g = lane >> 4;
  const int wr = w >> 1, wc = w & 1;

  f32x4 zero4 = {0.f, 0.f, 0.f, 0.f};
  f32x4 acc[4][4];
#pragma unroll
  for (int m = 0; m < 4; ++m)
#pragma unroll
    for (int n = 0; n < 4; ++n) acc[m][n] = zero4;

  const int sr = tid >> 3;            // 0..31: row within a 32-row round
  const int sk = tid & 7;             // 16B chunk within the 128B row

  auto STAGE = [&](int buf, int t) {
#pragma unroll
    for (int i = 0; i < 4; ++i) {
      int r = i * 32 + sr;
      int c = (sk ^ (r & 7)) << 3;    // inverse-swizzled global chunk
      GLDS(A  + (size_t)(bm + r) * K + t * 64 + c,
           sm + buf * 8192 + i * 2048 + w * 512);
      GLDS(Bt + (size_t)(bn + r) * K + t * 64 + c,
           sm + 16384 + buf * 8192 + i * 2048 + w * 512);
    }
  };

  const int nt = K >> 6;
  STAGE(0, 0);
  __syncthreads();
  int buf = 0;
  for (int t = 0; t < nt; ++t) {
    if (t + 1 < nt) STAGE(buf ^ 1, t + 1);     // async prefetch into other buffer
    const short* As = sm + buf * 8192;
    const short* Bs = sm + 16384 + buf * 8192;
#pragma unroll
    for (int kk = 0; kk < 2; ++kk) {
      bf16x8 la[4], lb[4];
#pragma unroll
      for (int m = 0; m < 4; ++m) {
        int row = wr * 64 + m * 16 + col;
        la[m] = *(const bf16x8*)(As + row * 64 + (((kk * 4 + g) ^ (row & 7)) << 3));
      }
#pragma unroll
      for (int n = 0; n < 4; ++n) {
        int row = wc * 64 + n * 16 + col;
        lb[n] = *(const bf16x8*)(Bs + row * 64 + (((kk * 4 + g) ^ (row & 7)) << 3));
      }
#pragma unroll
      for (int m = 0; m < 4; ++m)
#pragma unroll
        for (int n = 0; n < 4; ++n)
          acc[m][n] = __builtin_amdgcn_mfma_f32_16x16x32_bf16(la[m], lb[n], acc[m][n], 0, 0, 0);
    }
    __syncthreads();   // drains vmcnt(0)+lgkmcnt before barrier
    buf ^= 1;
  }

  const int orow0 = bm + wr * 64;
  const int ocol0 = bn + wc * 64;
  if (MODE == 0) {
    short* C = (short*)Cv;
#pragma unroll
    for (int m = 0; m < 4; ++m)
#pragma unroll
      for (int n = 0; n < 4; ++n)
#pragma unroll
        for (int r = 0; r < 4; ++r)
          C[(size_t)(orow0 + m * 16 + g * 4 + r) * N + ocol0 + n * 16 + col] =
              f2bf(acc[m][n][r]);
  } else if (MODE == 1) {
    float* C = (float*)Cv;
#pragma unroll
    for (int m = 0; m < 4; ++m)
#pragma unroll
      for (int n = 0; n < 4; ++n)
#pragma unroll
        for (int r = 0; r < 4; ++r)
          C[(size_t)(orow0 + m * 16 + g * 4 + r) * N + ocol0 + n * 16 + col] =
              acc[m][n][r];
  } else {
    short* C = (short*)Cv;
#pragma unroll
    for (int m = 0; m < 4; ++m)
#pragma unroll
      for (int n = 0; n < 4; ++n) {
        int grow = orow0 + m * 16 + g * 4;
        int bb = grow >> 11, s = grow & 2047;
        int cn = ocol0 + n * 16 + col;
        ushort4 pk;
        pk.x = (unsigned short)f2bf(acc[m][n][0]);
        pk.y = (unsigned short)f2bf(acc[m][n][1]);
        pk.z = (unsigned short)f2bf(acc[m][n][2]);
        pk.w = (unsigned short)f2bf(acc[m][n][3]);
        *(ushort4*)(C + ((size_t)(bb * 2048 + cn)) * 2048 + s) = pk;
      }
  }
}

// Dual-B fused wrappers (block-uniform branch; same K -> aligned barriers).
__global__ __launch_bounds__(256, 2) void gemm_qc(const short* __restrict__ xb,
                                                  const short* __restrict__ wqT,
                                                  const short* __restrict__ wcT,
                                                  short* __restrict__ qb,
                                                  short* __restrict__ kvb) {
  __shared__ alignas(16) short sm[32768];
  int x = blockIdx.x, y = blockIdx.y;
  if (x < 16) gemm_core<0>(xb, wqT, qb, 2048, 2048, y * 128, x * 128, sm);
  else        gemm_core<0>(xb, wcT, kvb, 512, 2048, y * 128, (x - 16) * 128, sm);
}
__global__ __launch_bounds__(256, 2) void gemm_kv(const short* __restrict__ kvb,
                                                  const short* __restrict__ wkT,
                                                  const short* __restrict__ wvT,
                                                  short* __restrict__ kb,
                                                  short* __restrict__ vtb) {
  __shared__ alignas(16) short sm[32768];
  int x = blockIdx.x, y = blockIdx.y;
  if (x < 16) gemm_core<0>(kvb, wkT, kb, 2048, 512, y * 128, x * 128, sm);
  else        gemm_core<2>(kvb, wvT, vtb, 2048, 512, y * 128, (x - 16) * 128, sm);
}
__global__ __launch_bounds__(256, 2) void gemm_wo(const short* __restrict__ obuf,
                                                  const short* __restrict__ woT,
                                                  float* __restrict__ out) {
  __shared__ alignas(16) short sm[32768];
  gemm_core<1>(obuf, woT, out, 2048, 2048, blockIdx.y * 128, blockIdx.x * 128, sm);
}

// ------------------------------------------------------------ attention ----
// Swapped-operand 32x32 (R4/R5/R8-frozen data path) with IN-BLOCK SPLIT-KV:
// block = 64 q-rows x 4 waves = (qsub 0,1) x (KV-stream s 0,1); each wave does
// 32 q-rows x 1024 keys (32 iters of the R8-verified KVBLK=32 body).
// -> 4096 waves total = 16 waves/CU (4/SIMD), 2x the R7 latency-hiding pool.
// K: LDS-staged per stream (2 streams x 8KB x dbuf = 32KB -> 4 blocks/CU).
// V: read directly from global (L2-resident, m169 pattern; no LDS, no swizzle).
// Post-loop flash-merge: s=1 waves publish (O^T f32, m, l) to LDS; s=0 waves
// combine O = O0*2^(m0-m) + O1*2^(m1-m) and run the R7 epilogue.
__global__ __launch_bounds__(256, 4) void attn_kernel(
    const short* __restrict__ qb, const short* __restrict__ kb,
    const short* __restrict__ vt, short* __restrict__ ob,
    const float* __restrict__ cosT, const float* __restrict__ sinT) {
  // shorts: K tile (stream s, buf b) @ (s*2+b)*4096 ([32 keys][128 d], 8KB each)
  // floats @ sm+16384: m/l [2 qsub][32 ql][2].  Merge O aliases K bufs.
  __shared__ alignas(16) short sm[16640];
  const int tid = threadIdx.x;
  const int lane = tid & 63, w = tid >> 6;
  const int qsub = w & 1, s = w >> 1;
  const int ql = lane & 31, hi = lane >> 5;
  const int qt = blockIdx.x >> 5, bh = blockIdx.x & 31;   // bid=qt*32+bh -> XCD=bh%8
  const int b = bh >> 4, h = bh & 15;
  const int q0 = qt * 64 + qsub * 32;
  const int qrow = q0 + ql;
  const int koff = s * 1024;

  // ---- Q load (B-fragment layout: lane q=ql, d = db*16 + hi*8 + j) + RoPE
  bf16x8 qf[8];
  {
    const short* qp = qb + ((size_t)(b * 2048 + qrow)) * 2048 + h * 128;
#pragma unroll
    for (int db = 0; db < 8; ++db) qf[db] = *(const bf16x8*)(qp + db * 16 + hi * 8);
    const float* cp = cosT + qrow * 32;
    const float* sp = sinT + qrow * 32;
#pragma unroll
    for (int db = 0; db < 2; ++db)
#pragma unroll
      for (int j = 0; j < 8; ++j) {
        int i = db * 16 + hi * 8 + j;
        float x1 = b2f(qf[db][j]), x2 = b2f(qf[db + 2][j]);
        float cv = cp[i], sv = sp[i];
        qf[db][j]     = f2bf(x1 * cv - x2 * sv);
        qf[db + 2][j] = f2bf(x1 * sv + x2 * cv);
      }
  }

  f32x16 o[4];
#pragma unroll
  for (int m4 = 0; m4 < 4; ++m4)
#pragma unroll
    for (int r = 0; r < 16; ++r) o[m4][r] = 0.f;
  float mrun = -3.0e38f, lrun = 0.f;

  // K stage: stream pair (2 waves, qsub splits rows); linear dest, inv-swz src.
  auto STAGE = [&](int buf, int kt) {
    const short* Kg = kb + ((size_t)(b * 2048 + koff + kt * 32)) * 2048 + h * 128;
    short* dst = sm + (s * 2 + buf) * 4096;
#pragma unroll
    for (int i = 0; i < 4; ++i) {
      int r = i * 8 + qsub * 4 + (lane >> 4);
      int cch = lane & 15;
      GLDS(Kg + (size_t)r * 2048 + ((cch ^ (r & 7)) << 3), dst + i * 1024 + qsub * 512);
    }
  };

  const float cl2 = 0.12752744590518352f;   // (1/sqrt(128)) * log2(e)
  const short* Vg = vt + ((size_t)(b * 2048 + h * 128)) * 2048 + koff;
  STAGE(0, 0);
  __syncthreads();
  int buf = 0;
  for (int kt = 0; kt < 32; ++kt) {
    if (kt + 1 < 32) STAGE(buf ^ 1, kt + 1);
    const short* Ks = sm + (s * 2 + buf) * 4096;

    // ---- QK^T (swapped): skt = S^T[32 keys][q], keys in regs (lane row=ql)
    f32x16 skt;
    __builtin_amdgcn_s_setprio(1);
    {
      f32x16 a;
#pragma unroll
      for (int r = 0; r < 16; ++r) a[r] = 0.f;
#pragma unroll
      for (int db = 0; db < 8; ++db) {
        bf16x8 kf = *(const bf16x8*)(Ks + ql * 128 + (((db * 2 + hi) ^ (ql & 7)) << 3));
        a = __builtin_amdgcn_mfma_f32_32x32x16_bf16(kf, qf[db], a, 0, 0, 0);
      }
#pragma unroll
      for (int r = 0; r < 16; ++r) skt[r] = a[r] * cl2;
    }
    __builtin_amdgcn_s_setprio(0);

    // ---- row-max (max tree + half-swap)
    float t0 = fmaxf(fmaxf(skt[0], skt[4]), fmaxf(skt[8], skt[12]));
    float t1 = fmaxf(fmaxf(skt[1], skt[5]), fmaxf(skt[9], skt[13]));
    float t2 = fmaxf(fmaxf(skt[2], skt[6]), fmaxf(skt[10], skt[14]));
    float t3 = fmaxf(fmaxf(skt[3], skt[7]), fmaxf(skt[11], skt[15]));
    float tmax = fmaxf(fmaxf(t0, t1), fmaxf(t2, t3));
    tmax = fmaxf(tmax, __shfl_xor(tmax, 32));

    // ---- defer-max (T13): rescale only when max grew by > 8 (log2 domain)
    if (!__all(tmax <= mrun + 8.0f)) {
      float mn = fmaxf(mrun, tmax);
      float fr = __builtin_amdgcn_exp2f(mrun - mn);
      mrun = mn;
      lrun *= fr;
#pragma unroll
      for (int m4 = 0; m4 < 4; ++m4)
#pragma unroll
        for (int r = 0; r < 16; ++r) o[m4][r] *= fr;
    }
    // ---- exp2 in place + row-sum
    float s0 = 0.f, s1 = 0.f, s2 = 0.f, s3 = 0.f;
#pragma unroll
    for (int r = 0; r < 16; r += 4) {
      skt[r]     = __builtin_amdgcn_exp2f(skt[r] - mrun);
      skt[r + 1] = __builtin_amdgcn_exp2f(skt[r + 1] - mrun);
      skt[r + 2] = __builtin_amdgcn_exp2f(skt[r + 2] - mrun);
      skt[r + 3] = __builtin_amdgcn_exp2f(skt[r + 3] - mrun);
      s0 += skt[r]; s1 += skt[r + 1]; s2 += skt[r + 2]; s3 += skt[r + 3];
    }
    float psum = (s0 + s1) + (s2 + s3);
    psum += __shfl_xor(psum, 32);
    lrun += psum;

    // ---- P -> bf16 P^T B-fragments (R4-frozen slot logic).
    // pf[half] element (hi,j) = P[ql][16*half + 8*hi + j].
    bf16x8 pf[2];
#pragma unroll
    for (int half = 0; half < 2; ++half) {
      unsigned a0 = cvtpk(skt[half * 8 + 0], skt[half * 8 + 1]);
      unsigned a1 = cvtpk(skt[half * 8 + 2], skt[half * 8 + 3]);
      unsigned b0 = cvtpk(skt[half * 8 + 4], skt[half * 8 + 5]);
      unsigned b1 = cvtpk(skt[half * 8 + 6], skt[half * 8 + 7]);
      unsigned pa0 = __shfl_xor(a0, 32), pa1 = __shfl_xor(a1, 32);
      unsigned pb0 = __shfl_xor(b0, 32), pb1 = __shfl_xor(b1, 32);
      union { unsigned u[4]; bf16x8 v; } tmp;
      tmp.u[0] = hi ? pb0 : a0;
      tmp.u[1] = hi ? pb1 : a1;
      tmp.u[2] = hi ? b0 : pa0;
      tmp.u[3] = hi ? b1 : pa1;
      pf[half] = tmp.v;
    }

    // ---- PV (swapped): O^T[d][q] += V^T @ P^T; V direct from global (L2)
    __builtin_amdgcn_s_setprio(1);
#pragma unroll
    for (int m4 = 0; m4 < 4; ++m4) {
      int rd = m4 * 32 + ql;
#pragma unroll
      for (int ks = 0; ks < 2; ++ks) {
        bf16x8 vf = *(const bf16x8*)(Vg + (size_t)rd * 2048 + kt * 32 + ((ks * 2 + hi) << 3));
        o[m4] = __builtin_amdgcn_mfma_f32_32x32x16_bf16(vf, pf[ks], o[m4], 0, 0, 0);
      }
    }
    __builtin_amdgcn_s_setprio(0);
    __syncthreads();
    buf ^= 1;
  }

  // ---- split-KV merge: s=1 publishes (O,m,l); s=0 combines + epilogue ----
  float* R  = (float*)sm;                  // [2 qsub][128 d][32 q] f32 (aliases K)
  float* ML = (float*)(sm + 16384);        // [2 qsub][32 ql][2]
  __syncthreads();
  if (s == 1) {
#pragma unroll
    for (int m4 = 0; m4 < 4; ++m4)
#pragma unroll
      for (int r = 0; r < 16; ++r) {
        int d = m4 * 32 + (r & 3) + 8 * (r >> 2) + 4 * hi;
        R[qsub * 4096 + d * 32 + ql] = o[m4][r];
      }
    if (hi == 0) {
      ML[qsub * 64 + ql * 2]     = mrun;
      ML[qsub * 64 + ql * 2 + 1] = lrun;
    }
  }
  __syncthreads();
  if (s == 1) return;

  float m1 = ML[qsub * 64 + ql * 2], l1 = ML[qsub * 64 + ql * 2 + 1];
  float mm = fmaxf(mrun, m1);
  float f0 = __builtin_amdgcn_exp2f(mrun - mm);
  float f1 = __builtin_amdgcn_exp2f(m1 - mm);
  float il = 1.0f / (lrun * f0 + l1 * f1);
#pragma unroll
  for (int m4 = 0; m4 < 4; ++m4)
#pragma unroll
    for (int r = 0; r < 16; ++r) {
      int d = m4 * 32 + (r & 3) + 8 * (r >> 2) + 4 * hi;
      o[m4][r] = o[m4][r] * f0 + R[qsub * 4096 + d * 32 + ql] * f1;
    }
  asm volatile("s_waitcnt lgkmcnt(0)" ::: "memory");   // merge reads done before E aliases

  // ---- epilogue (R7): O^T -> LDS transpose -> coalesced bf16 store.
  // E sits in this wave's own merge region (only this wave touches it now).
  short* E = sm + qsub * 8192;                 // [32 q][136 shorts]
#pragma unroll
  for (int m4 = 0; m4 < 4; ++m4)
#pragma unroll
    for (int r = 0; r < 16; r += 2) {
      int d = m4 * 32 + (r & 3) + 8 * (r >> 2) + 4 * hi;
      unsigned pk = cvtpk(o[m4][r] * il, o[m4][r + 1] * il);
      *(unsigned*)(E + ql * 136 + d) = pk;
    }
  asm volatile("s_waitcnt lgkmcnt(0)" ::: "memory");   // wave-private region
#pragma unroll
  for (int it = 0; it < 8; ++it) {
    int row = it * 4 + (lane >> 4);
    int ch = lane & 15;
    bf16x8 v = *(const bf16x8*)(E + row * 136 + ch * 8);
    *(bf16x8*)(ob + ((size_t)(b * 2048 + q0 + row)) * 2048 + h * 128 + ch * 8) = v;
  }
}

// --------------------------------------------------------------- launch ----
extern "C" void kernel_launch(void* const* d_in, const int* in_sizes, int n_in,
                              void* d_out, int out_size, void* d_ws, size_t ws_size,
                              hipStream_t stream) {
  (void)in_sizes; (void)n_in; (void)out_size; (void)ws_size;
  const float* x  = (const float*)d_in[0];
  const int*   pos = (const int*)d_in[1];
  const float* Wq = (const float*)d_in[2];
  const float* Wc = (const float*)d_in[3];
  const float* Wk = (const float*)d_in[4];
  const float* Wv = (const float*)d_in[5];
  const float* Wo = (const float*)d_in[6];

  char* ws = (char*)d_ws;
  short* xb   = (short*)(ws);                 // x bf16            16.78 MB
  short* qb   = (short*)(ws + 16777216);      // q (pre-rope)      16.78 MB
  short* kvb  = (short*)(ws + 33554432);      // latent            4.19 MB
  short* kb   = (short*)(ws + 37748736);      // k                 16.78 MB
  short* vtb  = (short*)(ws + 54525952);      // v transposed      16.78 MB
  short* obuf = (short*)(ws + 71303168);      // attn out          16.78 MB
  short* wqT  = (short*)(ws + 88080384);      // Wq^T              8.39 MB
  short* wcT  = (short*)(ws + 96468992);      // Wc^T              2.10 MB
  short* wkT  = (short*)(ws + 98566144);      // Wk^T              2.10 MB
  short* wvT  = (short*)(ws + 100663296);     // Wv^T              2.10 MB
  short* woT  = (short*)(ws + 102760448);     // Wo^T              8.39 MB
  float* cosT = (float*)(ws + 111149056);     // 0.26 MB
  float* sinT = (float*)(ws + 111411200);     // 0.26 MB

  cast4_kernel<<<8192, 256, 0, stream>>>(x, xb, 2097152);
  transpose_cast2_kernel<<<dim3(64, 64, 2), 256, 0, stream>>>(Wq, wqT, Wo, woT, 2048, 2048);
  transpose_cast2_kernel<<<dim3(16, 64, 1), 256, 0, stream>>>(Wc, wcT, Wc, wcT, 2048, 512);
  transpose_cast2_kernel<<<dim3(64, 16, 2), 256, 0, stream>>>(Wk, wkT, Wv, wvT, 512, 2048);
  rope_tab_kernel<<<256, 256, 0, stream>>>(pos, cosT, sinT);

  gemm_qc<<<dim3(20, 32), 256, 0, stream>>>(xb, wqT, wcT, qb, kvb);
  gemm_kv<<<dim3(32, 32), 256, 0, stream>>>(kvb, wkT, wvT, kb, vtb);

  attn_kernel<<<1024, 256, 0, stream>>>(qb, kb, vtb, obuf, cosT, sinT);

  gemm_wo<<<dim3(16, 32), 256, 0, stream>>>(obuf, woT, (float*)d_out);
}

// Round 10
// 240.237 us; speedup vs baseline: 1.5205x; 1.5205x over previous
//
#include <hip/hip_runtime.h>
#include <math.h>

// LatentCompressedAttention on MI355X (gfx950), bf16-MFMA pipeline.
// B=2, S=2048, D=2048, H=16, Dh=128, LATENT=512, ROPE=64.

typedef __attribute__((ext_vector_type(8))) short bf16x8;    // 8 bf16 in 4 VGPRs
typedef __attribute__((ext_vector_type(4))) float f32x4;
typedef __attribute__((ext_vector_type(16))) float f32x16;

#define GLDS(gp, lp)                                                         \
  __builtin_amdgcn_global_load_lds(                                          \
      (const __attribute__((address_space(1))) void*)(gp),                   \
      (__attribute__((address_space(3))) void*)(lp), 16, 0, 0)

__device__ __forceinline__ short f2bf(float f) {
  unsigned u = __builtin_bit_cast(unsigned, f);
  u += 0x7fffu + ((u >> 16) & 1u);          // RNE
  return (short)(u >> 16);
}
__device__ __forceinline__ float b2f(short x) {
  unsigned u = ((unsigned)(unsigned short)x) << 16;
  return __builtin_bit_cast(float, u);
}
// HW packed f32->bf16 (v_cvt_pk_bf16_f32; lo in low short)
__device__ __forceinline__ unsigned cvtpk(float lo, float hi) {
  unsigned r;
  asm("v_cvt_pk_bf16_f32 %0, %1, %2" : "=v"(r) : "v"(lo), "v"(hi));
  return r;
}

// ---------------------------------------------------------------- casts ----
__global__ void cast4_kernel(const float* __restrict__ x, short* __restrict__ xb, int n4) {
  int i = blockIdx.x * blockDim.x + threadIdx.x;
  if (i < n4) {
    float4 v = ((const float4*)x)[i];
    ushort4 o;
    o.x = (unsigned short)f2bf(v.x);
    o.y = (unsigned short)f2bf(v.y);
    o.z = (unsigned short)f2bf(v.z);
    o.w = (unsigned short)f2bf(v.w);
    ((ushort4*)xb)[i] = o;
  }
}

// W[K][N] fp32 -> Wt[N][K] bf16; gridDim.z selects one of two weight pairs.
__global__ void transpose_cast2_kernel(const float* __restrict__ W0, short* __restrict__ T0,
                                       const float* __restrict__ W1, short* __restrict__ T1,
                                       int K, int N) {
  const float* W = blockIdx.z ? W1 : W0;
  short* Wt = blockIdx.z ? T1 : T0;
  __shared__ float tile[32][33];
  int n0 = blockIdx.x * 32, k0 = blockIdx.y * 32;
  int tx = threadIdx.x & 31, ty = threadIdx.x >> 5;   // ty in 0..7
#pragma unroll
  for (int i = 0; i < 4; ++i)
    tile[ty + i * 8][tx] = W[(size_t)(k0 + ty + i * 8) * N + n0 + tx];
  __syncthreads();
#pragma unroll
  for (int i = 0; i < 4; ++i)
    Wt[(size_t)(n0 + ty + i * 8) * K + k0 + tx] = f2bf(tile[tx][ty + i * 8]);
}

// cos/sin table: [S=2048][32]
__global__ void rope_tab_kernel(const int* __restrict__ pos, float* __restrict__ cosT,
                                float* __restrict__ sinT) {
  int idx = blockIdx.x * 256 + threadIdx.x;
  if (idx < 2048 * 32) {
    int s = idx >> 5, i = idx & 31;
    float p = (float)pos[s];
    float freq = p * powf(10000.0f, -(float)(2 * i) / 64.0f);
    float sv, cv;
    sincosf(freq, &sv, &cv);
    cosT[idx] = cv;
    sinT[idx] = sv;
  }
}

// ----------------------------------------------------------------- GEMM ----
// R7-verified core. C = A[M,K] @ Bt[N,K]^T, bf16, 128x128 tile, BK=64,
// 4 waves, T2 XOR-swizzle (rule 21: linear dest + inv-swz source + swz read).
// NEW vs R7: MODE 0 epilogue goes through wave-private LDS (post-loop, LDS
// quiet, no barrier change) -> 8x bf16x8 stores instead of 64 scalar stores.
template <int MODE>
__device__ __forceinline__ void gemm_core(const short* __restrict__ A,
                                          const short* __restrict__ Bt,
                                          void* __restrict__ Cv,
                                          int N, int K, int bm, int bn,
                                          short* sm) {
  const int tid  = threadIdx.x;
  const int lane = tid & 63;
  const int w    = tid >> 6;
  const int col  = lane & 15, g = lane >> 4;
  const int wr = w >> 1, wc = w & 1;

  f32x4 zero4 = {0.f, 0.f, 0.f, 0.f};
  f32x4 acc[4][4];
#pragma unroll
  for (int m = 0; m < 4; ++m)
#pragma unroll
    for (int n = 0; n < 4; ++n) acc[m][n] = zero4;

  const int sr = tid >> 3;            // 0..31: row within a 32-row round
  const int sk = tid & 7;             // 16B chunk within the 128B row

  auto STAGE = [&](int buf, int t) {
#pragma unroll
    for (int i = 0; i < 4; ++i) {
      int r = i * 32 + sr;
      int c = (sk ^ (r & 7)) << 3;    // inverse-swizzled global chunk
      GLDS(A  + (size_t)(bm + r) * K + t * 64 + c,
           sm + buf * 8192 + i * 2048 + w * 512);
      GLDS(Bt + (size_t)(bn + r) * K + t * 64 + c,
           sm + 16384 + buf * 8192 + i * 2048 + w * 512);
    }
  };

  const int nt = K >> 6;
  STAGE(0, 0);
  __syncthreads();
  int buf = 0;
  for (int t = 0; t < nt; ++t) {
    if (t + 1 < nt) STAGE(buf ^ 1, t + 1);     // async prefetch into other buffer
    const short* As = sm + buf * 8192;
    const short* Bs = sm + 16384 + buf * 8192;
#pragma unroll
    for (int kk = 0; kk < 2; ++kk) {
      bf16x8 la[4], lb[4];
#pragma unroll
      for (int m = 0; m < 4; ++m) {
        int row = wr * 64 + m * 16 + col;
        la[m] = *(const bf16x8*)(As + row * 64 + (((kk * 4 + g) ^ (row & 7)) << 3));
      }
#pragma unroll
      for (int n = 0; n < 4; ++n) {
        int row = wc * 64 + n * 16 + col;
        lb[n] = *(const bf16x8*)(Bs + row * 64 + (((kk * 4 + g) ^ (row & 7)) << 3));
      }
#pragma unroll
      for (int m = 0; m < 4; ++m)
#pragma unroll
        for (int n = 0; n < 4; ++n)
          acc[m][n] = __builtin_amdgcn_mfma_f32_16x16x32_bf16(la[m], lb[n], acc[m][n], 0, 0, 0);
    }
    __syncthreads();   // drains vmcnt(0)+lgkmcnt before barrier
    buf ^= 1;
  }

  const int orow0 = bm + wr * 64;
  const int ocol0 = bn + wc * 64;
  if (MODE == 0) {
    // Vectorized epilogue: acc -> wave-private LDS [64][72] -> bf16x8 stores.
    // Post-loop: no prefetch in flight (last iter stages nothing), each wave
    // touches only its own region -> no barrier needed.
    short* C = (short*)Cv;
    short* E = sm + w * 4608;
#pragma unroll
    for (int m = 0; m < 4; ++m)
#pragma unroll
      for (int n = 0; n < 4; ++n)
#pragma unroll
        for (int r = 0; r < 4; ++r)
          E[(m * 16 + g * 4 + r) * 72 + n * 16 + col] = f2bf(acc[m][n][r]);
    asm volatile("s_waitcnt lgkmcnt(0)" ::: "memory");   // wave-private region
#pragma unroll
    for (int it = 0; it < 8; ++it) {
      int row = it * 8 + (lane >> 3);
      int ch = lane & 7;
      bf16x8 v = *(const bf16x8*)(E + row * 72 + ch * 8);
      *(bf16x8*)(C + (size_t)(orow0 + row) * N + ocol0 + ch * 8) = v;
    }
  } else if (MODE == 1) {
    float* C = (float*)Cv;
#pragma unroll
    for (int m = 0; m < 4; ++m)
#pragma unroll
      for (int n = 0; n < 4; ++n)
#pragma unroll
        for (int r = 0; r < 4; ++r)
          C[(size_t)(orow0 + m * 16 + g * 4 + r) * N + ocol0 + n * 16 + col] =
              acc[m][n][r];
  } else {
    // Vt[(b*2048 + n)*2048 + s]; 4 acc rows are 4 consecutive s -> one 8B store.
    short* C = (short*)Cv;
#pragma unroll
    for (int m = 0; m < 4; ++m)
#pragma unroll
      for (int n = 0; n < 4; ++n) {
        int grow = orow0 + m * 16 + g * 4;
        int bb = grow >> 11, s = grow & 2047;
        int cn = ocol0 + n * 16 + col;
        ushort4 pk;
        pk.x = (unsigned short)f2bf(acc[m][n][0]);
        pk.y = (unsigned short)f2bf(acc[m][n][1]);
        pk.z = (unsigned short)f2bf(acc[m][n][2]);
        pk.w = (unsigned short)f2bf(acc[m][n][3]);
        *(ushort4*)(C + ((size_t)(bb * 2048 + cn)) * 2048 + s) = pk;
      }
  }
}

// Dual-B fused wrappers (block-uniform branch; same K -> aligned barriers).
__global__ __launch_bounds__(256, 2) void gemm_qc(const short* __restrict__ xb,
                                                  const short* __restrict__ wqT,
                                                  const short* __restrict__ wcT,
                                                  short* __restrict__ qb,
                                                  short* __restrict__ kvb) {
  __shared__ alignas(16) short sm[32768];
  int x = blockIdx.x, y = blockIdx.y;
  if (x < 16) gemm_core<0>(xb, wqT, qb, 2048, 2048, y * 128, x * 128, sm);
  else        gemm_core<0>(xb, wcT, kvb, 512, 2048, y * 128, (x - 16) * 128, sm);
}
__global__ __launch_bounds__(256, 2) void gemm_kv(const short* __restrict__ kvb,
                                                  const short* __restrict__ wkT,
                                                  const short* __restrict__ wvT,
                                                  short* __restrict__ kb,
                                                  short* __restrict__ vtb) {
  __shared__ alignas(16) short sm[32768];
  int x = blockIdx.x, y = blockIdx.y;
  if (x < 16) gemm_core<0>(kvb, wkT, kb, 2048, 512, y * 128, x * 128, sm);
  else        gemm_core<2>(kvb, wvT, vtb, 2048, 512, y * 128, (x - 16) * 128, sm);
}
__global__ __launch_bounds__(256, 2) void gemm_wo(const short* __restrict__ obuf,
                                                  const short* __restrict__ woT,
                                                  float* __restrict__ out) {
  __shared__ alignas(16) short sm[32768];
  gemm_core<1>(obuf, woT, out, 2048, 2048, blockIdx.y * 128, blockIdx.x * 128, sm);
}

// ------------------------------------------------------------ attention ----
// R5/R7-VERIFIED structure (101us, passing), reverted from the R8/R9
// experiments.  Swapped-operand 32x32: S^T = K @ Q^T ; O^T = V^T @ P^T ;
// lane owns one q-row's softmax state.  XCD-locality 1D grid (bid%8 = bh%8),
// log2-domain softmax, defer-max THR=8, cvt_pk packing.  pf slots FROZEN (R4).
// NEW vs R7: QK per-kb2 accumulation split into two independent 4-long MFMA
// chains (halves the accumulator dependency chain); cl2 folded into combine.
__global__ __launch_bounds__(256, 2) void attn_kernel(
    const short* __restrict__ qb, const short* __restrict__ kb,
    const short* __restrict__ vt, short* __restrict__ ob,
    const float* __restrict__ cosT, const float* __restrict__ sinT) {
  // shorts: K bufs @0,8192 ([64 keys][128 d]); V bufs @16384,24576 ([128 d][64 keys])
  __shared__ alignas(16) short sm[32768];
  const int lane = threadIdx.x & 63, w = threadIdx.x >> 6;
  const int ql = lane & 31, hi = lane >> 5;
  const int qt = blockIdx.x >> 5, bh = blockIdx.x & 31;   // bid = qt*32+bh -> XCD=bh%8
  const int b = bh >> 4, h = bh & 15;
  const int q0w = qt * 128 + w * 32;
  const int qrow = q0w + ql;

  // ---- Q load (B-fragment layout: lane q=ql, d = db*16 + hi*8 + j) + RoPE
  bf16x8 qf[8];
  {
    const short* qp = qb + ((size_t)(b * 2048 + qrow)) * 2048 + h * 128;
#pragma unroll
    for (int db = 0; db < 8; ++db) qf[db] = *(const bf16x8*)(qp + db * 16 + hi * 8);
    const float* cp = cosT + qrow * 32;
    const float* sp = sinT + qrow * 32;
#pragma unroll
    for (int db = 0; db < 2; ++db)
#pragma unroll
      for (int j = 0; j < 8; ++j) {
        int i = db * 16 + hi * 8 + j;
        float x1 = b2f(qf[db][j]), x2 = b2f(qf[db + 2][j]);
        float cv = cp[i], sv = sp[i];
        qf[db][j]     = f2bf(x1 * cv - x2 * sv);
        qf[db + 2][j] = f2bf(x1 * sv + x2 * cv);
      }
  }

  f32x16 o[4];
#pragma unroll
  for (int m4 = 0; m4 < 4; ++m4)
#pragma unroll
    for (int r = 0; r < 16; ++r) o[m4][r] = 0.f;
  float mrun = -3.0e38f, lrun = 0.f;

  auto STAGE = [&](int buf, int kt) {
    // K tile [64 keys][128 d]: linear LDS dest, inverse-swizzled global src.
#pragma unroll
    for (int i = 0; i < 4; ++i) {
      int r = w * 16 + i * 4 + (lane >> 4);
      int cch = lane & 15;
      const short* gp = kb + ((size_t)(b * 2048 + kt * 64 + r)) * 2048 + h * 128 +
                        ((cch ^ (r & 7)) << 3);
      GLDS(gp, sm + buf * 8192 + w * 2048 + i * 512);
    }
    // V^T tile [128 d][64 keys]
#pragma unroll
    for (int i = 0; i < 4; ++i) {
      int rd = w * 32 + i * 8 + (lane >> 3);
      int cch = lane & 7;
      const short* gp = vt + ((size_t)(b * 2048 + h * 128 + rd)) * 2048 + kt * 64 +
                        ((cch ^ (rd & 7)) << 3);
      GLDS(gp, sm + 16384 + buf * 8192 + w * 2048 + i * 512);
    }
  };

  const float cl2 = 0.12752744590518352f;   // (1/sqrt(128)) * log2(e)
  STAGE(0, 0);
  __syncthreads();
  int buf = 0;
  for (int kt = 0; kt < 32; ++kt) {
    if (kt + 1 < 32) STAGE(buf ^ 1, kt + 1);
    const short* Ks = sm + buf * 8192;
    const short* Vs = sm + 16384 + buf * 8192;

    // ---- QK^T (swapped): skt[kb2] = S^T[key block kb2][q]; two independent
    // 4-long MFMA chains per kb2 (half the dep chain), cl2 folded in combine.
    f32x16 skt[2];
    __builtin_amdgcn_s_setprio(1);
#pragma unroll
    for (int kb2 = 0; kb2 < 2; ++kb2) {
      f32x16 a0, a1;
#pragma unroll
      for (int r = 0; r < 16; ++r) { a0[r] = 0.f; a1[r] = 0.f; }
      int krow = kb2 * 32 + ql;
#pragma unroll
      for (int db = 0; db < 4; ++db) {
        bf16x8 kf = *(const bf16x8*)(Ks + krow * 128 + (((db * 2 + hi) ^ (krow & 7)) << 3));
        a0 = __builtin_amdgcn_mfma_f32_32x32x16_bf16(kf, qf[db], a0, 0, 0, 0);
      }
#pragma unroll
      for (int db = 4; db < 8; ++db) {
        bf16x8 kf = *(const bf16x8*)(Ks + krow * 128 + (((db * 2 + hi) ^ (krow & 7)) << 3));
        a1 = __builtin_amdgcn_mfma_f32_32x32x16_bf16(kf, qf[db], a1, 0, 0, 0);
      }
#pragma unroll
      for (int r = 0; r < 16; ++r) skt[kb2][r] = (a0[r] + a1[r]) * cl2;
    }
    __builtin_amdgcn_s_setprio(0);

    // ---- row-max via max tree (4 chains of 8, then combine, then half-swap)
    float t0, t1, t2, t3;
    t0 = fmaxf(fmaxf(fmaxf(fmaxf(skt[0][0], skt[0][4]), skt[0][8]),
                     fmaxf(skt[0][12], skt[1][0])),
               fmaxf(fmaxf(skt[1][4], skt[1][8]), skt[1][12]));
    t1 = fmaxf(fmaxf(fmaxf(fmaxf(skt[0][1], skt[0][5]), skt[0][9]),
                     fmaxf(skt[0][13], skt[1][1])),
               fmaxf(fmaxf(skt[1][5], skt[1][9]), skt[1][13]));
    t2 = fmaxf(fmaxf(fmaxf(fmaxf(skt[0][2], skt[0][6]), skt[0][10]),
                     fmaxf(skt[0][14], skt[1][2])),
               fmaxf(fmaxf(skt[1][6], skt[1][10]), skt[1][14]));
    t3 = fmaxf(fmaxf(fmaxf(fmaxf(skt[0][3], skt[0][7]), skt[0][11]),
                     fmaxf(skt[0][15], skt[1][3])),
               fmaxf(fmaxf(skt[1][7], skt[1][11]), skt[1][15]));
    float tmax = fmaxf(fmaxf(t0, t1), fmaxf(t2, t3));
    tmax = fmaxf(tmax, __shfl_xor(tmax, 32));

    // ---- defer-max (T13): rescale only when max grew by > 8 (log2 domain)
    if (!__all(tmax <= mrun + 8.0f)) {
      float mn = fmaxf(mrun, tmax);
      float fr = __builtin_amdgcn_exp2f(mrun - mn);
      mrun = mn;
      lrun *= fr;
#pragma unroll
      for (int m4 = 0; m4 < 4; ++m4)
#pragma unroll
        for (int r = 0; r < 16; ++r) o[m4][r] *= fr;
    }
    // ---- exp2 in place + row-sum
    float s0 = 0.f, s1 = 0.f, s2 = 0.f, s3 = 0.f;
#pragma unroll
    for (int kb2 = 0; kb2 < 2; ++kb2)
#pragma unroll
      for (int r = 0; r < 16; r += 4) {
        skt[kb2][r]     = __builtin_amdgcn_exp2f(skt[kb2][r] - mrun);
        skt[kb2][r + 1] = __builtin_amdgcn_exp2f(skt[kb2][r + 1] - mrun);
        skt[kb2][r + 2] = __builtin_amdgcn_exp2f(skt[kb2][r + 2] - mrun);
        skt[kb2][r + 3] = __builtin_amdgcn_exp2f(skt[kb2][r + 3] - mrun);
        s0 += skt[kb2][r];     s1 += skt[kb2][r + 1];
        s2 += skt[kb2][r + 2]; s3 += skt[kb2][r + 3];
      }
    float psum = (s0 + s1) + (s2 + s3);
    psum += __shfl_xor(psum, 32);
    lrun += psum;

    // ---- P -> bf16 P^T B-fragments (slot assignment FROZEN from R4).
    bf16x8 pf[4];
#pragma unroll
    for (int kb2 = 0; kb2 < 2; ++kb2) {
#pragma unroll
      for (int half = 0; half < 2; ++half) {
        unsigned a0 = cvtpk(skt[kb2][half * 8 + 0], skt[kb2][half * 8 + 1]);
        unsigned a1 = cvtpk(skt[kb2][half * 8 + 2], skt[kb2][half * 8 + 3]);
        unsigned b0 = cvtpk(skt[kb2][half * 8 + 4], skt[kb2][half * 8 + 5]);
        unsigned b1 = cvtpk(skt[kb2][half * 8 + 6], skt[kb2][half * 8 + 7]);
        unsigned pa0 = __shfl_xor(a0, 32), pa1 = __shfl_xor(a1, 32);
        unsigned pb0 = __shfl_xor(b0, 32), pb1 = __shfl_xor(b1, 32);
        union { unsigned u[4]; bf16x8 v; } tmp;
        tmp.u[0] = hi ? pb0 : a0;
        tmp.u[1] = hi ? pb1 : a1;
        tmp.u[2] = hi ? b0 : pa0;
        tmp.u[3] = hi ? b1 : pa1;
        pf[kb2 * 2 + half] = tmp.v;
      }
    }

    // ---- PV (swapped): O^T[d][q] += V^T @ P^T
    __builtin_amdgcn_s_setprio(1);
#pragma unroll
    for (int m4 = 0; m4 < 4; ++m4) {
      int rd = m4 * 32 + ql;
#pragma unroll
      for (int ks = 0; ks < 4; ++ks) {
        bf16x8 vf = *(const bf16x8*)(Vs + rd * 64 + (((ks * 2 + hi) ^ (rd & 7)) << 3));
        o[m4] = __builtin_amdgcn_mfma_f32_32x32x16_bf16(vf, pf[ks], o[m4], 0, 0, 0);
      }
    }
    __builtin_amdgcn_s_setprio(0);
    __syncthreads();
    buf ^= 1;
  }

  // ---- epilogue: O^T -> LDS transpose (padded rows) -> coalesced bf16 store
  float il = 1.0f / lrun;
  short* E = sm + w * 4352;                    // [32 q][136 shorts], 16B-aligned rows
#pragma unroll
  for (int m4 = 0; m4 < 4; ++m4)
#pragma unroll
    for (int r = 0; r < 16; r += 2) {
      int d = m4 * 32 + (r & 3) + 8 * (r >> 2) + 4 * hi;
      unsigned pk = cvtpk(o[m4][r] * il, o[m4][r + 1] * il);
      *(unsigned*)(E + ql * 136 + d) = pk;
    }
  asm volatile("s_waitcnt lgkmcnt(0)" ::: "memory");   // wave-private region
#pragma unroll
  for (int it = 0; it < 8; ++it) {
    int row = it * 4 + (lane >> 4);
    int ch = lane & 15;
    bf16x8 v = *(const bf16x8*)(E + row * 136 + ch * 8);
    *(bf16x8*)(ob + ((size_t)(b * 2048 + q0w + row)) * 2048 + h * 128 + ch * 8) = v;
  }
}

// --------------------------------------------------------------- launch ----
extern "C" void kernel_launch(void* const* d_in, const int* in_sizes, int n_in,
                              void* d_out, int out_size, void* d_ws, size_t ws_size,
                              hipStream_t stream) {
  (void)in_sizes; (void)n_in; (void)out_size; (void)ws_size;
  const float* x  = (const float*)d_in[0];
  const int*   pos = (const int*)d_in[1];
  const float* Wq = (const float*)d_in[2];
  const float* Wc = (const float*)d_in[3];
  const float* Wk = (const float*)d_in[4];
  const float* Wv = (const float*)d_in[5];
  const float* Wo = (const float*)d_in[6];

  char* ws = (char*)d_ws;
  short* xb   = (short*)(ws);                 // x bf16            16.78 MB
  short* qb   = (short*)(ws + 16777216);      // q (pre-rope)      16.78 MB
  short* kvb  = (short*)(ws + 33554432);      // latent            4.19 MB
  short* kb   = (short*)(ws + 37748736);      // k                 16.78 MB
  short* vtb  = (short*)(ws + 54525952);      // v transposed      16.78 MB
  short* obuf = (short*)(ws + 71303168);      // attn out          16.78 MB
  short* wqT  = (short*)(ws + 88080384);      // Wq^T              8.39 MB
  short* wcT  = (short*)(ws + 96468992);      // Wc^T              2.10 MB
  short* wkT  = (short*)(ws + 98566144);      // Wk^T              2.10 MB
  short* wvT  = (short*)(ws + 100663296);     // Wv^T              2.10 MB
  short* woT  = (short*)(ws + 102760448);     // Wo^T              8.39 MB
  float* cosT = (float*)(ws + 111149056);     // 0.26 MB
  float* sinT = (float*)(ws + 111411200);     // 0.26 MB

  cast4_kernel<<<8192, 256, 0, stream>>>(x, xb, 2097152);
  transpose_cast2_kernel<<<dim3(64, 64, 2), 256, 0, stream>>>(Wq, wqT, Wo, woT, 2048, 2048);
  transpose_cast2_kernel<<<dim3(16, 64, 1), 256, 0, stream>>>(Wc, wcT, Wc, wcT, 2048, 512);
  transpose_cast2_kernel<<<dim3(64, 16, 2), 256, 0, stream>>>(Wk, wkT, Wv, wvT, 512, 2048);
  rope_tab_kernel<<<256, 256, 0, stream>>>(pos, cosT, sinT);

  gemm_qc<<<dim3(20, 32), 256, 0, stream>>>(xb, wqT, wcT, qb, kvb);
  gemm_kv<<<dim3(32, 32), 256, 0, stream>>>(kvb, wkT, wvT, kb, vtb);

  attn_kernel<<<512, 256, 0, stream>>>(qb, kb, vtb, obuf, cosT, sinT);

  gemm_wo<<<dim3(16, 32), 256, 0, stream>>>(obuf, woT, (float*)d_out);
}

// Round 11
// 223.486 us; speedup vs baseline: 1.6345x; 1.0750x over previous
//
#include <hip/hip_runtime.h>
#include <math.h>

// LatentCompressedAttention on MI355X (gfx950), bf16-MFMA pipeline.
// B=2, S=2048, D=2048, H=16, Dh=128, LATENT=512, ROPE=64.

typedef __attribute__((ext_vector_type(8))) short bf16x8;    // 8 bf16 in 4 VGPRs
typedef __attribute__((ext_vector_type(4))) float f32x4;
typedef __attribute__((ext_vector_type(16))) float f32x16;

#define GLDS(gp, lp)                                                         \
  __builtin_amdgcn_global_load_lds(                                          \
      (const __attribute__((address_space(1))) void*)(gp),                   \
      (__attribute__((address_space(3))) void*)(lp), 16, 0, 0)

__device__ __forceinline__ short f2bf(float f) {
  unsigned u = __builtin_bit_cast(unsigned, f);
  u += 0x7fffu + ((u >> 16) & 1u);          // RNE
  return (short)(u >> 16);
}
__device__ __forceinline__ float b2f(short x) {
  unsigned u = ((unsigned)(unsigned short)x) << 16;
  return __builtin_bit_cast(float, u);
}
// HW packed f32->bf16 (v_cvt_pk_bf16_f32; lo in low short)
__device__ __forceinline__ unsigned cvtpk(float lo, float hi) {
  unsigned r;
  asm("v_cvt_pk_bf16_f32 %0, %1, %2" : "=v"(r) : "v"(lo), "v"(hi));
  return r;
}

// ------------------------------------------------------------ fused prep ----
// One kernel for all preprocessing (saves launch gaps; cast overlaps
// transposes on otherwise-idle CUs).  Block ranges:
//   [0,8192)        cast x -> bf16
//   [8192,16384)    transpose Wq (z=0) / Wo (z=1), K=2048 N=2048
//   [16384,17408)   transpose Wc, K=2048 N=512
//   [17408,19456)   transpose Wk (z=0) / Wv (z=1), K=512 N=2048
//   [19456,19712)   rope cos/sin table [2048][32]
__device__ __forceinline__ void transpose_body(const float* __restrict__ W,
                                               short* __restrict__ Wt,
                                               int K, int N, int n0, int k0,
                                               float (*tile)[33]) {
  int tx = threadIdx.x & 31, ty = threadIdx.x >> 5;   // ty in 0..7
#pragma unroll
  for (int i = 0; i < 4; ++i)
    tile[ty + i * 8][tx] = W[(size_t)(k0 + ty + i * 8) * N + n0 + tx];
  __syncthreads();
#pragma unroll
  for (int i = 0; i < 4; ++i)
    Wt[(size_t)(n0 + ty + i * 8) * K + k0 + tx] = f2bf(tile[tx][ty + i * 8]);
}

__global__ void prep_kernel(const float* __restrict__ x, short* __restrict__ xb,
                            const float* __restrict__ Wq, short* __restrict__ wqT,
                            const float* __restrict__ Wo, short* __restrict__ woT,
                            const float* __restrict__ Wc, short* __restrict__ wcT,
                            const float* __restrict__ Wk, short* __restrict__ wkT,
                            const float* __restrict__ Wv, short* __restrict__ wvT,
                            const int* __restrict__ pos, float* __restrict__ cosT,
                            float* __restrict__ sinT) {
  __shared__ float tile[32][33];
  const int bid = blockIdx.x;
  if (bid < 8192) {
    int i = bid * 256 + threadIdx.x;            // n4 = 2097152 exactly
    float4 v = ((const float4*)x)[i];
    ushort4 o;
    o.x = (unsigned short)f2bf(v.x);
    o.y = (unsigned short)f2bf(v.y);
    o.z = (unsigned short)f2bf(v.z);
    o.w = (unsigned short)f2bf(v.w);
    ((ushort4*)xb)[i] = o;
  } else if (bid < 16384) {
    int local = bid - 8192;
    int z = local >> 12, rem = local & 4095;
    transpose_body(z ? Wo : Wq, z ? woT : wqT, 2048, 2048,
                   (rem & 63) * 32, (rem >> 6) * 32, tile);
  } else if (bid < 17408) {
    int local = bid - 16384;
    transpose_body(Wc, wcT, 2048, 512, (local & 15) * 32, (local >> 4) * 32, tile);
  } else if (bid < 19456) {
    int local = bid - 17408;
    int z = local >> 10, rem = local & 1023;
    transpose_body(z ? Wv : Wk, z ? wvT : wkT, 512, 2048,
                   (rem & 63) * 32, (rem >> 6) * 32, tile);
  } else {
    int idx = (bid - 19456) * 256 + threadIdx.x;   // 65536 = 2048*32 exactly
    int s = idx >> 5, i = idx & 31;
    float p = (float)pos[s];
    float freq = p * powf(10000.0f, -(float)(2 * i) / 64.0f);
    float sv, cv;
    sincosf(freq, &sv, &cv);
    cosT[idx] = cv;
    sinT[idx] = sv;
  }
}

// ----------------------------------------------------------------- GEMM ----
// R7-verified core. C = A[M,K] @ Bt[N,K]^T, bf16, 128x128 tile, BK=64,
// 4 waves, T2 XOR-swizzle (rule 21: linear dest + inv-swz source + swz read).
// MODE 0 epilogue: direct scalar stores (R7 form; the R10 LDS-roundtrip
// variant cost ~12us across the MODE-0 GEMMs -- reverted).
template <int MODE>
__device__ __forceinline__ void gemm_core(const short* __restrict__ A,
                                          const short* __restrict__ Bt,
                                          void* __restrict__ Cv,
                                          int N, int K, int bm, int bn,
                                          short* sm) {
  const int tid  = threadIdx.x;
  const int lane = tid & 63;
  const int w    = tid >> 6;
  const int col  = lane & 15, g = lane >> 4;
  const int wr = w >> 1, wc = w & 1;

  f32x4 zero4 = {0.f, 0.f, 0.f, 0.f};
  f32x4 acc[4][4];
#pragma unroll
  for (int m = 0; m < 4; ++m)
#pragma unroll
    for (int n = 0; n < 4; ++n) acc[m][n] = zero4;

  const int sr = tid >> 3;            // 0..31: row within a 32-row round
  const int sk = tid & 7;             // 16B chunk within the 128B row

  auto STAGE = [&](int buf, int t) {
#pragma unroll
    for (int i = 0; i < 4; ++i) {
      int r = i * 32 + sr;
      int c = (sk ^ (r & 7)) << 3;    // inverse-swizzled global chunk
      GLDS(A  + (size_t)(bm + r) * K + t * 64 + c,
           sm + buf * 8192 + i * 2048 + w * 512);
      GLDS(Bt + (size_t)(bn + r) * K + t * 64 + c,
           sm + 16384 + buf * 8192 + i * 2048 + w * 512);
    }
  };

  const int nt = K >> 6;
  STAGE(0, 0);
  __syncthreads();
  int buf = 0;
  for (int t = 0; t < nt; ++t) {
    if (t + 1 < nt) STAGE(buf ^ 1, t + 1);     // async prefetch into other buffer
    const short* As = sm + buf * 8192;
    const short* Bs = sm + 16384 + buf * 8192;
#pragma unroll
    for (int kk = 0; kk < 2; ++kk) {
      bf16x8 la[4], lb[4];
#pragma unroll
      for (int m = 0; m < 4; ++m) {
        int row = wr * 64 + m * 16 + col;
        la[m] = *(const bf16x8*)(As + row * 64 + (((kk * 4 + g) ^ (row & 7)) << 3));
      }
#pragma unroll
      for (int n = 0; n < 4; ++n) {
        int row = wc * 64 + n * 16 + col;
        lb[n] = *(const bf16x8*)(Bs + row * 64 + (((kk * 4 + g) ^ (row & 7)) << 3));
      }
#pragma unroll
      for (int m = 0; m < 4; ++m)
#pragma unroll
        for (int n = 0; n < 4; ++n)
          acc[m][n] = __builtin_amdgcn_mfma_f32_16x16x32_bf16(la[m], lb[n], acc[m][n], 0, 0, 0);
    }
    __syncthreads();   // drains vmcnt(0)+lgkmcnt before barrier
    buf ^= 1;
  }

  const int orow0 = bm + wr * 64;
  const int ocol0 = bn + wc * 64;
  if (MODE == 0) {
    short* C = (short*)Cv;
#pragma unroll
    for (int m = 0; m < 4; ++m)
#pragma unroll
      for (int n = 0; n < 4; ++n)
#pragma unroll
        for (int r = 0; r < 4; ++r)
          C[(size_t)(orow0 + m * 16 + g * 4 + r) * N + ocol0 + n * 16 + col] =
              f2bf(acc[m][n][r]);
  } else if (MODE == 1) {
    float* C = (float*)Cv;
#pragma unroll
    for (int m = 0; m < 4; ++m)
#pragma unroll
      for (int n = 0; n < 4; ++n)
#pragma unroll
        for (int r = 0; r < 4; ++r)
          C[(size_t)(orow0 + m * 16 + g * 4 + r) * N + ocol0 + n * 16 + col] =
              acc[m][n][r];
  } else {
    // Vt[(b*2048 + n)*2048 + s]; 4 acc rows are 4 consecutive s -> one 8B store.
    short* C = (short*)Cv;
#pragma unroll
    for (int m = 0; m < 4; ++m)
#pragma unroll
      for (int n = 0; n < 4; ++n) {
        int grow = orow0 + m * 16 + g * 4;
        int bb = grow >> 11, s = grow & 2047;
        int cn = ocol0 + n * 16 + col;
        ushort4 pk;
        pk.x = (unsigned short)f2bf(acc[m][n][0]);
        pk.y = (unsigned short)f2bf(acc[m][n][1]);
        pk.z = (unsigned short)f2bf(acc[m][n][2]);
        pk.w = (unsigned short)f2bf(acc[m][n][3]);
        *(ushort4*)(C + ((size_t)(bb * 2048 + cn)) * 2048 + s) = pk;
      }
  }
}

// Dual-B fused wrappers (block-uniform branch; same K -> aligned barriers).
__global__ __launch_bounds__(256, 2) void gemm_qc(const short* __restrict__ xb,
                                                  const short* __restrict__ wqT,
                                                  const short* __restrict__ wcT,
                                                  short* __restrict__ qb,
                                                  short* __restrict__ kvb) {
  __shared__ alignas(16) short sm[32768];
  int x = blockIdx.x, y = blockIdx.y;
  if (x < 16) gemm_core<0>(xb, wqT, qb, 2048, 2048, y * 128, x * 128, sm);
  else        gemm_core<0>(xb, wcT, kvb, 512, 2048, y * 128, (x - 16) * 128, sm);
}
__global__ __launch_bounds__(256, 2) void gemm_kv(const short* __restrict__ kvb,
                                                  const short* __restrict__ wkT,
                                                  const short* __restrict__ wvT,
                                                  short* __restrict__ kb,
                                                  short* __restrict__ vtb) {
  __shared__ alignas(16) short sm[32768];
  int x = blockIdx.x, y = blockIdx.y;
  if (x < 16) gemm_core<0>(kvb, wkT, kb, 2048, 512, y * 128, x * 128, sm);
  else        gemm_core<2>(kvb, wvT, vtb, 2048, 512, y * 128, (x - 16) * 128, sm);
}
__global__ __launch_bounds__(256, 2) void gemm_wo(const short* __restrict__ obuf,
                                                  const short* __restrict__ woT,
                                                  float* __restrict__ out) {
  __shared__ alignas(16) short sm[32768];
  gemm_core<1>(obuf, woT, out, 2048, 2048, blockIdx.y * 128, blockIdx.x * 128, sm);
}

// ------------------------------------------------------------ attention ----
// R10-VERIFIED kernel, byte-identical (97.7us, passing).  Swapped-operand
// 32x32: S^T = K @ Q^T ; O^T = V^T @ P^T ; lane owns one q-row's softmax
// state.  XCD-locality 1D grid (bid%8 = bh%8), log2-domain softmax,
// defer-max THR=8, cvt_pk packing, split QK accumulator chains.
// pf slot assignment FROZEN from R4.
__global__ __launch_bounds__(256, 2) void attn_kernel(
    const short* __restrict__ qb, const short* __restrict__ kb,
    const short* __restrict__ vt, short* __restrict__ ob,
    const float* __restrict__ cosT, const float* __restrict__ sinT) {
  // shorts: K bufs @0,8192 ([64 keys][128 d]); V bufs @16384,24576 ([128 d][64 keys])
  __shared__ alignas(16) short sm[32768];
  const int lane = threadIdx.x & 63, w = threadIdx.x >> 6;
  const int ql = lane & 31, hi = lane >> 5;
  const int qt = blockIdx.x >> 5, bh = blockIdx.x & 31;   // bid = qt*32+bh -> XCD=bh%8
  const int b = bh >> 4, h = bh & 15;
  const int q0w = qt * 128 + w * 32;
  const int qrow = q0w + ql;

  // ---- Q load (B-fragment layout: lane q=ql, d = db*16 + hi*8 + j) + RoPE
  bf16x8 qf[8];
  {
    const short* qp = qb + ((size_t)(b * 2048 + qrow)) * 2048 + h * 128;
#pragma unroll
    for (int db = 0; db < 8; ++db) qf[db] = *(const bf16x8*)(qp + db * 16 + hi * 8);
    const float* cp = cosT + qrow * 32;
    const float* sp = sinT + qrow * 32;
#pragma unroll
    for (int db = 0; db < 2; ++db)
#pragma unroll
      for (int j = 0; j < 8; ++j) {
        int i = db * 16 + hi * 8 + j;
        float x1 = b2f(qf[db][j]), x2 = b2f(qf[db + 2][j]);
        float cv = cp[i], sv = sp[i];
        qf[db][j]     = f2bf(x1 * cv - x2 * sv);
        qf[db + 2][j] = f2bf(x1 * sv + x2 * cv);
      }
  }

  f32x16 o[4];
#pragma unroll
  for (int m4 = 0; m4 < 4; ++m4)
#pragma unroll
    for (int r = 0; r < 16; ++r) o[m4][r] = 0.f;
  float mrun = -3.0e38f, lrun = 0.f;

  auto STAGE = [&](int buf, int kt) {
    // K tile [64 keys][128 d]: linear LDS dest, inverse-swizzled global src.
#pragma unroll
    for (int i = 0; i < 4; ++i) {
      int r = w * 16 + i * 4 + (lane >> 4);
      int cch = lane & 15;
      const short* gp = kb + ((size_t)(b * 2048 + kt * 64 + r)) * 2048 + h * 128 +
                        ((cch ^ (r & 7)) << 3);
      GLDS(gp, sm + buf * 8192 + w * 2048 + i * 512);
    }
    // V^T tile [128 d][64 keys]
#pragma unroll
    for (int i = 0; i < 4; ++i) {
      int rd = w * 32 + i * 8 + (lane >> 3);
      int cch = lane & 7;
      const short* gp = vt + ((size_t)(b * 2048 + h * 128 + rd)) * 2048 + kt * 64 +
                        ((cch ^ (rd & 7)) << 3);
      GLDS(gp, sm + 16384 + buf * 8192 + w * 2048 + i * 512);
    }
  };

  const float cl2 = 0.12752744590518352f;   // (1/sqrt(128)) * log2(e)
  STAGE(0, 0);
  __syncthreads();
  int buf = 0;
  for (int kt = 0; kt < 32; ++kt) {
    if (kt + 1 < 32) STAGE(buf ^ 1, kt + 1);
    const short* Ks = sm + buf * 8192;
    const short* Vs = sm + 16384 + buf * 8192;

    // ---- QK^T (swapped): skt[kb2] = S^T[key block kb2][q]; two independent
    // 4-long MFMA chains per kb2 (half the dep chain), cl2 folded in combine.
    f32x16 skt[2];
    __builtin_amdgcn_s_setprio(1);
#pragma unroll
    for (int kb2 = 0; kb2 < 2; ++kb2) {
      f32x16 a0, a1;
#pragma unroll
      for (int r = 0; r < 16; ++r) { a0[r] = 0.f; a1[r] = 0.f; }
      int krow = kb2 * 32 + ql;
#pragma unroll
      for (int db = 0; db < 4; ++db) {
        bf16x8 kf = *(const bf16x8*)(Ks + krow * 128 + (((db * 2 + hi) ^ (krow & 7)) << 3));
        a0 = __builtin_amdgcn_mfma_f32_32x32x16_bf16(kf, qf[db], a0, 0, 0, 0);
      }
#pragma unroll
      for (int db = 4; db < 8; ++db) {
        bf16x8 kf = *(const bf16x8*)(Ks + krow * 128 + (((db * 2 + hi) ^ (krow & 7)) << 3));
        a1 = __builtin_amdgcn_mfma_f32_32x32x16_bf16(kf, qf[db], a1, 0, 0, 0);
      }
#pragma unroll
      for (int r = 0; r < 16; ++r) skt[kb2][r] = (a0[r] + a1[r]) * cl2;
    }
    __builtin_amdgcn_s_setprio(0);

    // ---- row-max via max tree (4 chains of 8, then combine, then half-swap)
    float t0, t1, t2, t3;
    t0 = fmaxf(fmaxf(fmaxf(fmaxf(skt[0][0], skt[0][4]), skt[0][8]),
                     fmaxf(skt[0][12], skt[1][0])),
               fmaxf(fmaxf(skt[1][4], skt[1][8]), skt[1][12]));
    t1 = fmaxf(fmaxf(fmaxf(fmaxf(skt[0][1], skt[0][5]), skt[0][9]),
                     fmaxf(skt[0][13], skt[1][1])),
               fmaxf(fmaxf(skt[1][5], skt[1][9]), skt[1][13]));
    t2 = fmaxf(fmaxf(fmaxf(fmaxf(skt[0][2], skt[0][6]), skt[0][10]),
                     fmaxf(skt[0][14], skt[1][2])),
               fmaxf(fmaxf(skt[1][6], skt[1][10]), skt[1][14]));
    t3 = fmaxf(fmaxf(fmaxf(fmaxf(skt[0][3], skt[0][7]), skt[0][11]),
                     fmaxf(skt[0][15], skt[1][3])),
               fmaxf(fmaxf(skt[1][7], skt[1][11]), skt[1][15]));
    float tmax = fmaxf(fmaxf(t0, t1), fmaxf(t2, t3));
    tmax = fmaxf(tmax, __shfl_xor(tmax, 32));

    // ---- defer-max (T13): rescale only when max grew by > 8 (log2 domain)
    if (!__all(tmax <= mrun + 8.0f)) {
      float mn = fmaxf(mrun, tmax);
      float fr = __builtin_amdgcn_exp2f(mrun - mn);
      mrun = mn;
      lrun *= fr;
#pragma unroll
      for (int m4 = 0; m4 < 4; ++m4)
#pragma unroll
        for (int r = 0; r < 16; ++r) o[m4][r] *= fr;
    }
    // ---- exp2 in place + row-sum
    float s0 = 0.f, s1 = 0.f, s2 = 0.f, s3 = 0.f;
#pragma unroll
    for (int kb2 = 0; kb2 < 2; ++kb2)
#pragma unroll
      for (int r = 0; r < 16; r += 4) {
        skt[kb2][r]     = __builtin_amdgcn_exp2f(skt[kb2][r] - mrun);
        skt[kb2][r + 1] = __builtin_amdgcn_exp2f(skt[kb2][r + 1] - mrun);
        skt[kb2][r + 2] = __builtin_amdgcn_exp2f(skt[kb2][r + 2] - mrun);
        skt[kb2][r + 3] = __builtin_amdgcn_exp2f(skt[kb2][r + 3] - mrun);
        s0 += skt[kb2][r];     s1 += skt[kb2][r + 1];
        s2 += skt[kb2][r + 2]; s3 += skt[kb2][r + 3];
      }
    float psum = (s0 + s1) + (s2 + s3);
    psum += __shfl_xor(psum, 32);
    lrun += psum;

    // ---- P -> bf16 P^T B-fragments (slot assignment FROZEN from R4).
    bf16x8 pf[4];
#pragma unroll
    for (int kb2 = 0; kb2 < 2; ++kb2) {
#pragma unroll
      for (int half = 0; half < 2; ++half) {
        unsigned a0 = cvtpk(skt[kb2][half * 8 + 0], skt[kb2][half * 8 + 1]);
        unsigned a1 = cvtpk(skt[kb2][half * 8 + 2], skt[kb2][half * 8 + 3]);
        unsigned b0 = cvtpk(skt[kb2][half * 8 + 4], skt[kb2][half * 8 + 5]);
        unsigned b1 = cvtpk(skt[kb2][half * 8 + 6], skt[kb2][half * 8 + 7]);
        unsigned pa0 = __shfl_xor(a0, 32), pa1 = __shfl_xor(a1, 32);
        unsigned pb0 = __shfl_xor(b0, 32), pb1 = __shfl_xor(b1, 32);
        union { unsigned u[4]; bf16x8 v; } tmp;
        tmp.u[0] = hi ? pb0 : a0;
        tmp.u[1] = hi ? pb1 : a1;
        tmp.u[2] = hi ? b0 : pa0;
        tmp.u[3] = hi ? b1 : pa1;
        pf[kb2 * 2 + half] = tmp.v;
      }
    }

    // ---- PV (swapped): O^T[d][q] += V^T @ P^T
    __builtin_amdgcn_s_setprio(1);
#pragma unroll
    for (int m4 = 0; m4 < 4; ++m4) {
      int rd = m4 * 32 + ql;
#pragma unroll
      for (int ks = 0; ks < 4; ++ks) {
        bf16x8 vf = *(const bf16x8*)(Vs + rd * 64 + (((ks * 2 + hi) ^ (rd & 7)) << 3));
        o[m4] = __builtin_amdgcn_mfma_f32_32x32x16_bf16(vf, pf[ks], o[m4], 0, 0, 0);
      }
    }
    __builtin_amdgcn_s_setprio(0);
    __syncthreads();
    buf ^= 1;
  }

  // ---- epilogue: O^T -> LDS transpose (padded rows) -> coalesced bf16 store
  float il = 1.0f / lrun;
  short* E = sm + w * 4352;                    // [32 q][136 shorts], 16B-aligned rows
#pragma unroll
  for (int m4 = 0; m4 < 4; ++m4)
#pragma unroll
    for (int r = 0; r < 16; r += 2) {
      int d = m4 * 32 + (r & 3) + 8 * (r >> 2) + 4 * hi;
      unsigned pk = cvtpk(o[m4][r] * il, o[m4][r + 1] * il);
      *(unsigned*)(E + ql * 136 + d) = pk;
    }
  asm volatile("s_waitcnt lgkmcnt(0)" ::: "memory");   // wave-private region
#pragma unroll
  for (int it = 0; it < 8; ++it) {
    int row = it * 4 + (lane >> 4);
    int ch = lane & 15;
    bf16x8 v = *(const bf16x8*)(E + row * 136 + ch * 8);
    *(bf16x8*)(ob + ((size_t)(b * 2048 + q0w + row)) * 2048 + h * 128 + ch * 8) = v;
  }
}

// --------------------------------------------------------------- launch ----
extern "C" void kernel_launch(void* const* d_in, const int* in_sizes, int n_in,
                              void* d_out, int out_size, void* d_ws, size_t ws_size,
                              hipStream_t stream) {
  (void)in_sizes; (void)n_in; (void)out_size; (void)ws_size;
  const float* x  = (const float*)d_in[0];
  const int*   pos = (const int*)d_in[1];
  const float* Wq = (const float*)d_in[2];
  const float* Wc = (const float*)d_in[3];
  const float* Wk = (const float*)d_in[4];
  const float* Wv = (const float*)d_in[5];
  const float* Wo = (const float*)d_in[6];

  char* ws = (char*)d_ws;
  short* xb   = (short*)(ws);                 // x bf16            16.78 MB
  short* qb   = (short*)(ws + 16777216);      // q (pre-rope)      16.78 MB
  short* kvb  = (short*)(ws + 33554432);      // latent            4.19 MB
  short* kb   = (short*)(ws + 37748736);      // k                 16.78 MB
  short* vtb  = (short*)(ws + 54525952);      // v transposed      16.78 MB
  short* obuf = (short*)(ws + 71303168);      // attn out          16.78 MB
  short* wqT  = (short*)(ws + 88080384);      // Wq^T              8.39 MB
  short* wcT  = (short*)(ws + 96468992);      // Wc^T              2.10 MB
  short* wkT  = (short*)(ws + 98566144);      // Wk^T              2.10 MB
  short* wvT  = (short*)(ws + 100663296);     // Wv^T              2.10 MB
  short* woT  = (short*)(ws + 102760448);     // Wo^T              8.39 MB
  float* cosT = (float*)(ws + 111149056);     // 0.26 MB
  float* sinT = (float*)(ws + 111411200);     // 0.26 MB

  prep_kernel<<<19712, 256, 0, stream>>>(x, xb, Wq, wqT, Wo, woT, Wc, wcT,
                                         Wk, wkT, Wv, wvT, pos, cosT, sinT);

  gemm_qc<<<dim3(20, 32), 256, 0, stream>>>(xb, wqT, wcT, qb, kvb);
  gemm_kv<<<dim3(32, 32), 256, 0, stream>>>(kvb, wkT, wvT, kb, vtb);

  attn_kernel<<<512, 256, 0, stream>>>(qb, kb, vtb, obuf, cosT, sinT);

  gemm_wo<<<dim3(16, 32), 256, 0, stream>>>(obuf, woT, (float*)d_out);
}